// Round 11
// baseline (278.540 us; speedup 1.0000x reference)
//
#include <hip/hip_runtime.h>
#include <stdint.h>

#define TT 25
#define SS 512
#define BB 4096
#define ROWS 16
#define NBLK (BB / ROWS)        // 256
#define EMROW (SS * TT)         // 12800
#define SLOT 448                // dwords per em ring slot (400 used + pad)
#define PRE 6                   // prefetch depth in steps
#define IL2 1.4426950408889634f
#define LN2F 0.6931471805599453f

typedef int   v2i __attribute__((ext_vector_type(2)));
typedef float v4f __attribute__((ext_vector_type(4)));

#define AS1 __attribute__((address_space(1)))
#define AS3 __attribute__((address_space(3)))
#define GLLDS4(SRC, DST)  __builtin_amdgcn_global_load_lds((const AS1 void*)(SRC), (AS3 void*)(DST), 4, 0, 0)
#define GLLDS16(SRC, DST) __builtin_amdgcn_global_load_lds((const AS1 void*)(SRC), (AS3 void*)(DST), 16, 0, 0)

__device__ __forceinline__ float ex2(float x){ return __builtin_amdgcn_exp2f(x); }
__device__ __forceinline__ float lg2(float x){ return __builtin_amdgcn_logf(x); }

// exact RNE f32 -> bf16 (prologue only)
__device__ __forceinline__ uint32_t bf16rne(float f){
  uint32_t u = __float_as_uint(f);
  return (u + 0x7FFFu + ((u >> 16) & 1u)) >> 16;
}
__device__ __forceinline__ float bf16tof(uint32_t h){ return __uint_as_float(h << 16); }

__device__ __forceinline__ float bperm(int addr, float v){
  return __int_as_float(__builtin_amdgcn_ds_bpermute(addr, __float_as_int(v)));
}
#define SWZ(v,P) __int_as_float(__builtin_amdgcn_ds_swizzle(__float_as_int(v), P))

__device__ __forceinline__ v4f mfma16(v2i a, v2i b, v4f c){
  v4f d;
  asm("v_mfma_f32_16x16x16_bf16 %0, %1, %2, %3" : "=v"(d) : "v"(a), "v"(b), "v"(c));
  return d;
}
__device__ __forceinline__ uint32_t cvtpk(float lo, float hi){
  uint32_t r;
  asm("v_cvt_pk_bf16_f32 %0, %1, %2" : "=v"(r) : "v"(lo), "v"(hi));
  return r;
}

// mask may arrive as bool(u8), int32, or float32 — detect from first element
__device__ __forceinline__ int mask_at(const void* m, int mode, int idx){
  if (mode == 1) return ((const int*)m)[idx] != 0;
  if (mode == 2) return ((const float*)m)[idx] != 0.0f;
  return ((const unsigned char*)m)[idx] != 0;
}

__global__ __launch_bounds__(64)
void crf_mfma(const float* __restrict__ em, const float* __restrict__ startp,
              const float* __restrict__ endp, const float* __restrict__ transp,
              const int* __restrict__ labels, const void* __restrict__ maskp,
              float* __restrict__ wsr, float* __restrict__ wsl)
{
  __shared__ float lds_em[8 * SLOT];   // em ring: 8 slots x 448 dwords
  __shared__ float lds_tr[640];        // trans table (625 used)
  __shared__ int   lds_lab[ROWS * SS]; // 16 label rows

  const int lane = threadIdx.x;        // 0..63
  const int m = lane & 15;             // row-id within the 16-row group
  const int g = lane >> 4;
  const int b0 = blockIdx.x * ROWS;

  const uint32_t w0 = ((const uint32_t*)maskp)[0];
  const int mode = (w0 == 1u) ? 1 : ((w0 == 0x3F800000u) ? 2 : 0);

  // ---- stage labels (16 contiguous rows = 32 KB) : 32 x 16B-per-lane ----
  {
    const int* src0 = labels + b0 * SS;
#pragma unroll
    for (int i = 0; i < 32; ++i)
      GLLDS16(src0 + i * 256 + lane * 4, ((char*)lds_lab) + i * 1024);
  }
  // ---- stage trans table : 10 x 4B ----
#pragma unroll
  for (int i = 0; i < 10; ++i) {
    int idx = i * 64 + lane; idx = idx > 624 ? 624 : idx;
    GLLDS4(transp + idx, ((char*)lds_tr) + i * 256);
  }

  // ---- per-lane row length via binary search on prefix mask (L in [256,512]) ----
  int Lm = 256;
  {
    int base = (b0 + m) * SS;
#pragma unroll
    for (int d = 128; d >= 1; d >>= 1)
      if (mask_at(maskp, mode, base + Lm + d - 1)) Lm += d;
  }
  float Lf = (float)Lm;
  Lf = fmaxf(Lf, SWZ(Lf, 0x041F)); Lf = fmaxf(Lf, SWZ(Lf, 0x081F));
  Lf = fmaxf(Lf, SWZ(Lf, 0x101F)); Lf = fmaxf(Lf, SWZ(Lf, 0x201F));
  const int maxL = __builtin_amdgcn_readfirstlane((int)Lf);

  // ---- A fragments: E^T[j][k] = exp(trans[k][j]), split hi+lo bf16 (exact RNE) ----
  // A layout (16x16x16): M-row = lane&15 (local j), k = 4*(lane>>4) + q, pairs lo|hi<<16
  v2i Ah00, Ah01, Ah10, Ah11, Al00, Al01, Al10, Al11;
  {
#define BUILD_A(JH, KH, AH, AL)                                             \
    {                                                                       \
      uint32_t hq[4], lq[4];                                                \
      _Pragma("unroll")                                                     \
      for (int q = 0; q < 4; ++q) {                                         \
        int j = (JH)*16 + m, k = (KH)*16 + 4*g + q;                         \
        float e = 0.f;                                                      \
        if (j < TT && k < TT) e = ex2(transp[k*TT + j] * IL2);              \
        uint32_t h = bf16rne(e);                                            \
        uint32_t l = bf16rne(e - bf16tof(h));                               \
        hq[q] = h; lq[q] = l;                                               \
      }                                                                     \
      AH.x = (int)(hq[0] | (hq[1] << 16)); AH.y = (int)(hq[2] | (hq[3] << 16)); \
      AL.x = (int)(lq[0] | (lq[1] << 16)); AL.y = (int)(lq[2] | (lq[3] << 16)); \
    }
    BUILD_A(0, 0, Ah00, Al00)
    BUILD_A(0, 1, Ah01, Al01)
    BUILD_A(1, 0, Ah10, Al10)
    BUILD_A(1, 1, Ah11, Al11)
#undef BUILD_A
  }

  // ---- init state B = bf16(alpha0), alpha0 = exp(start + em0) ----
  v2i B1, B2;
  {
    uint32_t p[4];
#pragma unroll
    for (int q = 0; q < 4; ++q) {
      int j = 4*g + q;
      p[q] = bf16rne(ex2((startp[j] + em[(size_t)(b0 + m) * EMROW + j]) * IL2));
    }
    B1.x = (int)(p[0] | (p[1] << 16)); B1.y = (int)(p[2] | (p[3] << 16));
#pragma unroll
    for (int q = 0; q < 4; ++q) {
      int j = 16 + 4*g + q;
      float a0 = 0.f;
      if (j < TT) a0 = ex2((startp[j] + em[(size_t)(b0 + m) * EMROW + j]) * IL2);
      p[q] = bf16rne(a0);
    }
    B2.x = (int)(p[0] | (p[1] << 16)); B2.y = (int)(p[2] | (p[3] << 16));
  }

  // ---- numerator init (global gathers, before the drain) ----
  int l_prev = labels[(b0 + m) * SS];
  float num = startp[l_prev] + em[(size_t)(b0 + m) * EMROW + l_prev];
  int C2 = 0;

  // ---- drain all prologue VMEM so the in-loop vmcnt count is pure ----
  asm volatile("s_waitcnt vmcnt(0)" ::: "memory");
  int l_cur = lds_lab[m * SS + 1];

  // ---- em stage per-lane offsets + prologue stage of slots ts=1..6 ----
  int voff0, voff1, voff2, voff3, voff4, voff5, voff6;
  {
    int vo[7];
#pragma unroll
    for (int i = 0; i < 7; ++i) {
      int f = i * 64 + lane;
      int r = f / TT, j = f - r * TT;
      if (f >= 400) { r = 15; j = 24; }
      vo[i] = (b0 + r) * EMROW + j + TT;   // position for ts = 1
    }
    voff0 = vo[0]; voff1 = vo[1]; voff2 = vo[2]; voff3 = vo[3];
    voff4 = vo[4]; voff5 = vo[5]; voff6 = vo[6];
  }
#define STAGE7(SB)                                                          \
  { GLLDS4(em + voff0, ((char*)lds_em) + (SB) + 0 * 256);                   \
    GLLDS4(em + voff1, ((char*)lds_em) + (SB) + 1 * 256);                   \
    GLLDS4(em + voff2, ((char*)lds_em) + (SB) + 2 * 256);                   \
    GLLDS4(em + voff3, ((char*)lds_em) + (SB) + 3 * 256);                   \
    GLLDS4(em + voff4, ((char*)lds_em) + (SB) + 4 * 256);                   \
    GLLDS4(em + voff5, ((char*)lds_em) + (SB) + 5 * 256);                   \
    GLLDS4(em + voff6, ((char*)lds_em) + (SB) + 6 * 256); }
#define ADV7 { voff0 += TT; voff1 += TT; voff2 += TT; voff3 += TT;          \
               voff4 += TT; voff5 += TT; voff6 += TT; }
#pragma unroll
  for (int ts = 1; ts <= PRE; ++ts) {
    STAGE7(ts * 1792)
    if (ts < PRE) ADV7
  }

  v4f zero4 = {0.f, 0.f, 0.f, 0.f};
  asm volatile("" : "+v"(Ah00), "+v"(Ah01), "+v"(Ah10), "+v"(Ah11),
                    "+v"(Al00), "+v"(Al01), "+v"(Al10), "+v"(Al11), "+v"(zero4));

  const int c_off = m * TT + 4 * g;   // dword offset of this lane's em block

  // =================== main recursion ===================
  for (int t = 1; t < maxL; ++t) {
    // stage slot t+PRE (clamped; uniform advance keeps counting exact: 7 VMEM/iter)
    {
      int ts = t + PRE;
      if (ts <= maxL - 1) { ADV7 } else ts = maxL - 1;
      STAGE7((ts & 7) * 1792)
    }
    // oldest 7 (slot t) complete once <= 42 outstanding
    asm volatile("s_waitcnt vmcnt(42)" ::: "memory");

    const int cb = (t & 7) * SLOT;
    int tnext = t + 1; if (tnext > SS - 1) tnext = SS - 1;
    int l_next = lds_lab[m * SS + tnext];
    float tv = lds_tr[l_prev * TT + l_cur];
    float en = lds_em[cb + m * TT + l_cur];

    float e0 = lds_em[cb + c_off + 0],  e1 = lds_em[cb + c_off + 1];
    float e2 = lds_em[cb + c_off + 2],  e3 = lds_em[cb + c_off + 3];
    float f0 = lds_em[cb + c_off + 16], f1 = lds_em[cb + c_off + 17];
    float f2 = lds_em[cb + c_off + 18], f3 = lds_em[cb + c_off + 19];

    // D = (E_lo + E_hi) x P   (8 MFMAs, fp32 acc)
    v4f D0 = mfma16(Al00, B1, zero4);
    D0 = mfma16(Al01, B2, D0);
    D0 = mfma16(Ah00, B1, D0);
    D0 = mfma16(Ah01, B2, D0);
    v4f D1 = mfma16(Al10, B1, zero4);
    D1 = mfma16(Al11, B2, D1);
    D1 = mfma16(Ah10, B1, D1);
    D1 = mfma16(Ah11, B2, D1);

    // emission (fp32)
    D0.x *= ex2(e0 * IL2); D0.y *= ex2(e1 * IL2);
    D0.z *= ex2(e2 * IL2); D0.w *= ex2(e3 * IL2);
    D1.x *= ex2(f0 * IL2); D1.y *= ex2(f1 * IL2);
    D1.z *= ex2(f2 * IL2); D1.w *= ex2(f3 * IL2);

    bool live = t < Lm;

    if ((t & 7) == 0) {   // exact power-of-2 rescale, per row m
      float mx = fmaxf(fmaxf(fmaxf(D0.x, D0.y), fmaxf(D0.z, D0.w)),
                       fmaxf(fmaxf(D1.x, D1.y), fmaxf(D1.z, D1.w)));
      mx = fmaxf(mx, SWZ(mx, 0x401F));            // combine g pairs (xor 16)
      mx = fmaxf(mx, bperm(4 * (lane ^ 32), mx)); // combine across 32-boundary
      int ef = (__float_as_int(mx) >> 23) & 0xFF;
      float sc = __int_as_float((254 - ef) << 23);
      D0.x *= sc; D0.y *= sc; D0.z *= sc; D0.w *= sc;
      D1.x *= sc; D1.y *= sc; D1.z *= sc; D1.w *= sc;
      C2 += live ? (ef - 127) : 0;                // frozen rows: state discarded anyway
    }

    // pack -> next B (RNE cvt), freeze dead rows
    {
      uint32_t n0 = cvtpk(D0.x, D0.y), n1 = cvtpk(D0.z, D0.w);
      uint32_t n2 = cvtpk(D1.x, D1.y), n3 = cvtpk(D1.z, D1.w);
      B1.x = live ? (int)n0 : B1.x;  B1.y = live ? (int)n1 : B1.y;
      B2.x = live ? (int)n2 : B2.x;  B2.y = live ? (int)n3 : B2.y;
    }

    num += live ? (tv + en) : 0.f;
    l_prev = l_cur; l_cur = l_next;
  }
#undef STAGE7
#undef ADV7

  // =================== epilogue ===================
  // logZ_m = ln( sum_j alpha[j] * exp(end[j]) ) + C2*ln2
  float term = 0.f;
  {
    uint32_t u;
    float s, ee;
#define ACC(U, HI, J)                                                       \
    { u = (uint32_t)(U); s = bf16tof(HI ? (u >> 16) : (u & 0xFFFFu));       \
      int j = (J); ee = (j < TT) ? ex2(endp[j] * IL2) : 0.f;                \
      term = fmaf(s, ee, term); }
    ACC(B1.x, 0, 4*g + 0)  ACC(B1.x, 1, 4*g + 1)
    ACC(B1.y, 0, 4*g + 2)  ACC(B1.y, 1, 4*g + 3)
    ACC(B2.x, 0, 16 + 4*g + 0)  ACC(B2.x, 1, 16 + 4*g + 1)
    ACC(B2.y, 0, 16 + 4*g + 2)  ACC(B2.y, 1, 16 + 4*g + 3)
#undef ACC
  }
  term += SWZ(term, 0x401F);
  term += bperm(4 * (lane ^ 32), term);
  float logZ = LN2F * (lg2(term) + (float)C2);

  int lend = lds_lab[m * SS + Lm - 1];
  num += endp[lend];

  if (lane < 16) {
    wsr[b0 + m] = num - logZ;
    wsl[b0 + m] = (float)Lm;
  }
}

__global__ void crf_reduce(const float* __restrict__ wsr,
                           const float* __restrict__ wsl,
                           float* __restrict__ out)
{
  __shared__ float sr[256], sl[256];
  int t = threadIdx.x;
  float a = 0.0f, c = 0.0f;
  for (int i = t; i < BB; i += 256) { a += wsr[i]; c += wsl[i]; }
  sr[t] = a; sl[t] = c;
  __syncthreads();
  for (int k = 128; k > 0; k >>= 1) {
    if (t < k) { sr[t] += sr[t + k]; sl[t] += sl[t + k]; }
    __syncthreads();
  }
  if (t == 0) out[0] = sr[0] / sl[0];
}

extern "C" void kernel_launch(void* const* d_in, const int* in_sizes, int n_in,
                              void* d_out, int out_size, void* d_ws, size_t ws_size,
                              hipStream_t stream)
{
  const float* em = (const float*)d_in[0];
  const float* st = (const float*)d_in[1];
  const float* en = (const float*)d_in[2];
  const float* tr = (const float*)d_in[3];
  const int*   lb = (const int*)d_in[4];
  const void*  mk = d_in[5];
  float* wsr = (float*)d_ws;
  float* wsl = wsr + BB;
  crf_mfma<<<NBLK, 64, 0, stream>>>(em, st, en, tr, lb, mk, wsr, wsl);
  crf_reduce<<<1, 256, 0, stream>>>(wsr, wsl, (float*)d_out);
}

// Round 12
// 126.587 us; speedup vs baseline: 2.2004x; 2.2004x over previous
//
#include <hip/hip_runtime.h>
#include <stdint.h>

#define TT 25
#define SS 512
#define BB 4096
#define ROWS 16
#define NRG (BB / ROWS)          // 256 row-groups
#define NSEG 4
#define EMROW (SS * TT)          // 12800
#define RST32 32                 // lds em row stride (dwords)
#define SLOT (ROWS * RST32)      // 512 dwords per ring slot
#define WARM 24
#define PRE 6
#define IL2 1.4426950408889634f
#define LN2F 0.6931471805599453f

typedef int   v2i __attribute__((ext_vector_type(2)));
typedef float v4f __attribute__((ext_vector_type(4)));

#define AS1 __attribute__((address_space(1)))
#define AS3 __attribute__((address_space(3)))
#define GLLDS4(SRC, DST) __builtin_amdgcn_global_load_lds((const AS1 void*)(SRC), (AS3 void*)(DST), 4, 0, 0)

__device__ __forceinline__ float ex2(float x){ return __builtin_amdgcn_exp2f(x); }
__device__ __forceinline__ float lg2(float x){ return __builtin_amdgcn_logf(x); }
__device__ __forceinline__ uint32_t bf16rne(float f){
  uint32_t u = __float_as_uint(f);
  return (u + 0x7FFFu + ((u >> 16) & 1u)) >> 16;
}
__device__ __forceinline__ float bf16tof(uint32_t h){ return __uint_as_float(h << 16); }
__device__ __forceinline__ float bpermf(int addr, float v){
  return __int_as_float(__builtin_amdgcn_ds_bpermute(addr, __float_as_int(v)));
}
#define SWZ(v,P) __int_as_float(__builtin_amdgcn_ds_swizzle(__float_as_int(v), P))

__device__ __forceinline__ v4f mfma16(v2i a, v2i b, v4f c){
  v4f d;
  asm("v_mfma_f32_16x16x16_bf16 %0, %1, %2, %3" : "=v"(d) : "v"(a), "v"(b), "v"(c));
  return d;
}
__device__ __forceinline__ uint32_t cvtpk(float lo, float hi){
  uint32_t r;
  asm("v_cvt_pk_bf16_f32 %0, %1, %2" : "=v"(r) : "v"(lo), "v"(hi));
  return r;
}
__device__ __forceinline__ int mask_at(const void* m, int mode, int idx){
  if (mode == 1) return ((const int*)m)[idx] != 0;
  if (mode == 2) return ((const float*)m)[idx] != 0.0f;
  return ((const unsigned char*)m)[idx] != 0;
}

__global__ __launch_bounds__(64)
void crf_seg(const float* __restrict__ em, const float* __restrict__ startp,
             const float* __restrict__ endp, const float* __restrict__ transp,
             const int* __restrict__ labels, const void* __restrict__ maskp,
             float* __restrict__ wsseg, float* __restrict__ wsl)
{
  __shared__ __align__(16) float lds_em[8 * SLOT];   // 16 KB ring
  __shared__ float lds_tr[640];

  const int lane = threadIdx.x;
  const int m = lane & 15, g = lane >> 4;
  const int rg = blockIdx.x & (NRG - 1);
  const int q  = (blockIdx.x >> 8) + 1;              // 1..4
  const int b0 = rg * ROWS;

  const uint32_t w0 = ((const uint32_t*)maskp)[0];
  const int mode = (w0 == 1u) ? 1 : ((w0 == 0x3F800000u) ? 2 : 0);

  // ---- stage trans table ----
#pragma unroll
  for (int i = 0; i < 10; ++i) {
    int idx = i * 64 + lane; idx = idx > 624 ? 624 : idx;
    GLLDS4(transp + idx, ((char*)lds_tr) + i * 256);
  }

  // ---- per-lane row length (binary search on prefix mask, L in [256,512]) ----
  int Lm = 256;
  {
    int base = (b0 + m) * SS;
#pragma unroll
    for (int d = 128; d >= 1; d >>= 1)
      if (mask_at(maskp, mode, base + Lm + d - 1)) Lm += d;
  }
  const int LM1 = Lm - 1;
  const int bq  = (q * LM1) >> 2;          // segment end position
  const int bqm = ((q - 1) * LM1) >> 2;    // segment start position
  const int W   = (q > 1) ? WARM : 0;
  const int pstart = bqm - W;              // state known/seeded at this position
  const int Iown = W + (bq - bqm);         // live iterations for this row
  float If = (float)Iown;
  If = fmaxf(If, SWZ(If, 0x041F)); If = fmaxf(If, SWZ(If, 0x081F));
  If = fmaxf(If, SWZ(If, 0x101F)); If = fmaxf(If, SWZ(If, 0x201F));
  const int Imax = __builtin_amdgcn_readfirstlane((int)If);

  // ---- A fragments: E^T[j][k] = exp(trans[k][j]), hi+lo bf16 split ----
  v2i Ah00, Ah01, Ah10, Ah11, Al00, Al01, Al10, Al11;
  {
#define BUILD_A(JH, KH, AH, AL)                                             \
    {                                                                       \
      uint32_t hq[4], lq[4];                                                \
      _Pragma("unroll")                                                     \
      for (int qq = 0; qq < 4; ++qq) {                                      \
        int j = (JH)*16 + m, k = (KH)*16 + 4*g + qq;                        \
        float e = 0.f;                                                      \
        if (j < TT && k < TT) e = ex2(transp[k*TT + j] * IL2);              \
        uint32_t h = bf16rne(e);                                            \
        uint32_t l = bf16rne(e - bf16tof(h));                               \
        hq[qq] = h; lq[qq] = l;                                             \
      }                                                                     \
      AH.x = (int)(hq[0] | (hq[1] << 16)); AH.y = (int)(hq[2] | (hq[3] << 16)); \
      AL.x = (int)(lq[0] | (lq[1] << 16)); AL.y = (int)(lq[2] | (lq[3] << 16)); \
    }
    BUILD_A(0, 0, Ah00, Al00)
    BUILD_A(0, 1, Ah01, Al01)
    BUILD_A(1, 0, Ah10, Al10)
    BUILD_A(1, 1, Ah11, Al11)
#undef BUILD_A
  }

  // ---- B init ----
  v2i B1, B2;
  float num = 0.f; int C2 = 0;
  int l_prev;
  if (q == 1) {
    uint32_t p[4];
#pragma unroll
    for (int qq = 0; qq < 4; ++qq) {
      int j = 4*g + qq;
      p[qq] = bf16rne(ex2((startp[j] + em[(size_t)(b0 + m) * EMROW + j]) * IL2));
    }
    B1.x = (int)(p[0] | (p[1] << 16)); B1.y = (int)(p[2] | (p[3] << 16));
#pragma unroll
    for (int qq = 0; qq < 4; ++qq) {
      int j = 16 + 4*g + qq;
      float a0 = 0.f;
      if (j < TT) a0 = ex2((startp[j] + em[(size_t)(b0 + m) * EMROW + j]) * IL2);
      p[qq] = bf16rne(a0);
    }
    B2.x = (int)(p[0] | (p[1] << 16)); B2.y = (int)(p[2] | (p[3] << 16));
    l_prev = labels[(b0 + m) * SS];
    num = startp[l_prev] + em[(size_t)(b0 + m) * EMROW + l_prev];
  } else {
    // ones in valid cols (warmup seed; contraction forgets it in 24 steps)
    B1.x = 0x3F803F80; B1.y = 0x3F803F80;
    B2.x = (g == 0 || g == 1) ? 0x3F803F80 : (g == 2 ? 0x00003F80 : 0);
    B2.y = (g == 0 || g == 1) ? 0x3F803F80 : 0;
    l_prev = labels[(b0 + m) * SS + pstart];
  }

  // ---- label ring (depth 4, registers) : l_cur(i) = labels[lbase + 1 + i] ----
  const int lbase = (b0 + m) * SS + pstart;
  const int rowend = (b0 + m) * SS + (SS - 1);
  int lab0 = labels[lbase + 1], lab1 = labels[lbase + 2];
  int lab2 = labels[lbase + 3], lab3 = labels[lbase + 4];
  int labOff = lbase + 5;

  // ---- em staging voffs (8): lane covers dst f = u*64+lane -> r=f>>5, js=f&31,
  //      logical col j = js ^ ((r&7)<<2) (XOR swizzle pre-applied on source) ----
  int voff0, voff1, voff2, voff3, voff4, voff5, voff6, voff7;
  {
#define MKVOFF(U, V)                                                        \
    { int r_ = 2*(U) + (lane >> 5);                                         \
      int pst_ = __builtin_amdgcn_ds_bpermute(4 * r_, pstart);              \
      int j_ = (lane & 31) ^ ((r_ & 7) << 2);                               \
      int jc_ = j_ > 24 ? 24 : j_;                                          \
      V = (b0 + r_) * EMROW + (pst_ + 1) * TT + jc_; }
    MKVOFF(0, voff0) MKVOFF(1, voff1) MKVOFF(2, voff2) MKVOFF(3, voff3)
    MKVOFF(4, voff4) MKVOFF(5, voff5) MKVOFF(6, voff6) MKVOFF(7, voff7)
#undef MKVOFF
  }

  // drain all prologue VMEM so in-loop counting is pure
  asm volatile("s_waitcnt vmcnt(0)" ::: "memory");

#define STAGE8(SB)                                                          \
  { GLLDS4(em + voff0, ((char*)lds_em) + (SB) + 0 * 256);                   \
    GLLDS4(em + voff1, ((char*)lds_em) + (SB) + 1 * 256);                   \
    GLLDS4(em + voff2, ((char*)lds_em) + (SB) + 2 * 256);                   \
    GLLDS4(em + voff3, ((char*)lds_em) + (SB) + 3 * 256);                   \
    GLLDS4(em + voff4, ((char*)lds_em) + (SB) + 4 * 256);                   \
    GLLDS4(em + voff5, ((char*)lds_em) + (SB) + 5 * 256);                   \
    GLLDS4(em + voff6, ((char*)lds_em) + (SB) + 6 * 256);                   \
    GLLDS4(em + voff7, ((char*)lds_em) + (SB) + 7 * 256); }
#define ADV8 { voff0 += TT; voff1 += TT; voff2 += TT; voff3 += TT;          \
               voff4 += TT; voff5 += TT; voff6 += TT; voff7 += TT; }

#pragma unroll
  for (int ts = 0; ts < PRE; ++ts) {
    STAGE8(ts * (SLOT * 4))
    if (ts < PRE - 1) ADV8
  }

  v4f zero4 = {0.f, 0.f, 0.f, 0.f};
  asm volatile("" : "+v"(Ah00), "+v"(Ah01), "+v"(Ah10), "+v"(Ah11),
                    "+v"(Al00), "+v"(Al01), "+v"(Al10), "+v"(Al11), "+v"(zero4));

  const int xr = (m & 7) << 2;
  const int eoff1 = m * RST32 + ((4 * g) ^ xr);
  const int eoff2 = m * RST32 + ((16 + 4 * g) ^ xr);
  const int enbase = m * RST32;

  v2i Br1 = B1, Br2 = B2; int Cref = 0; float numref = 0.f;

#define STEP(U, LV)                                                         \
  {                                                                         \
    const int it = ibase + (U);                                             \
    if (it + PRE <= Imax - 1) ADV8                                          \
    int ts = it + PRE; if (ts > Imax - 1) ts = Imax - 1;                    \
    STAGE8((ts & 7) * (SLOT * 4))                                           \
    int lo_ = labOff > rowend ? rowend : labOff;                            \
    int nl = labels[lo_]; ++labOff;                                         \
    asm volatile("s_waitcnt vmcnt(49)" ::: "memory");                       \
    const int cb = (U) * SLOT;                                              \
    float4 E0 = *(const float4*)&lds_em[cb + eoff1];                        \
    float4 E1 = *(const float4*)&lds_em[cb + eoff2];                        \
    int l_cur = LV; LV = nl;                                                \
    float tv = lds_tr[l_prev * TT + l_cur];                                 \
    float en = lds_em[cb + enbase + (l_cur ^ xr)];                          \
    float e0 = ex2(E0.x * IL2), e1 = ex2(E0.y * IL2);                       \
    float e2 = ex2(E0.z * IL2), e3 = ex2(E0.w * IL2);                       \
    float f0 = ex2(E1.x * IL2), f1 = ex2(E1.y * IL2);                       \
    float f2 = ex2(E1.z * IL2), f3 = ex2(E1.w * IL2);                       \
    v4f X0 = mfma16(Ah00, B1, mfma16(Al00, B1, zero4));                     \
    v4f Y0 = mfma16(Ah01, B2, mfma16(Al01, B2, zero4));                     \
    v4f X1 = mfma16(Ah10, B1, mfma16(Al10, B1, zero4));                     \
    v4f Y1 = mfma16(Ah11, B2, mfma16(Al11, B2, zero4));                     \
    v4f D0 = X0 + Y0, D1 = X1 + Y1;                                         \
    D0.x *= e0; D0.y *= e1; D0.z *= e2; D0.w *= e3;                         \
    D1.x *= f0; D1.y *= f1; D1.z *= f2; D1.w *= f3;                         \
    bool live = it < Iown;                                                  \
    if ((U) == 7) {                                                         \
      float mx = fmaxf(fmaxf(fmaxf(D0.x, D0.y), fmaxf(D0.z, D0.w)),         \
                       fmaxf(fmaxf(D1.x, D1.y), fmaxf(D1.z, D1.w)));        \
      mx = fmaxf(mx, SWZ(mx, 0x401F));                                      \
      mx = fmaxf(mx, bpermf(4 * (lane ^ 32), mx));                          \
      int ef = (__float_as_int(mx) >> 23) & 0xFF;                           \
      float sc = __int_as_float((254 - ef) << 23);                          \
      D0.x *= sc; D0.y *= sc; D0.z *= sc; D0.w *= sc;                       \
      D1.x *= sc; D1.y *= sc; D1.z *= sc; D1.w *= sc;                       \
      C2 += live ? (ef - 127) : 0;                                          \
    }                                                                       \
    uint32_t n0 = cvtpk(D0.x, D0.y), n1 = cvtpk(D0.z, D0.w);                \
    uint32_t n2 = cvtpk(D1.x, D1.y), n3 = cvtpk(D1.z, D1.w);                \
    B1.x = live ? (int)n0 : B1.x;  B1.y = live ? (int)n1 : B1.y;            \
    B2.x = live ? (int)n2 : B2.x;  B2.y = live ? (int)n3 : B2.y;            \
    num += live ? (tv + en) : 0.f;                                          \
    l_prev = l_cur;                                                         \
    if ((U) == 7 && q > 1 && it == WARM - 1) {                              \
      Br1 = B1; Br2 = B2; Cref = C2; numref = num;                          \
    }                                                                       \
  }

  int ibase = 0;
  for (; ibase + 8 <= Imax; ibase += 8) {
    STEP(0, lab0) STEP(1, lab1) STEP(2, lab2) STEP(3, lab3)
    STEP(4, lab0) STEP(5, lab1) STEP(6, lab2) STEP(7, lab3)
  }
  {
    int rem = Imax - ibase;    // 0..7 (no rescale needed: <8 since last one)
    if (rem > 0) STEP(0, lab0)
    if (rem > 1) STEP(1, lab1)
    if (rem > 2) STEP(2, lab2)
    if (rem > 3) STEP(3, lab3)
    if (rem > 4) STEP(4, lab0)
    if (rem > 5) STEP(5, lab1)
    if (rem > 6) STEP(6, lab2)
  }
#undef STEP
#undef STAGE8
#undef ADV8

  // ---- epilogue: R_q = [C2 + lg2 phi'(B_end)] - [Cref + lg2 phi(Bref)] ----
  float wj[8], wp[8];
#pragma unroll
  for (int d = 0; d < 8; ++d) {
    int j = (d < 4) ? (4 * g + d) : (16 + 4 * g + (d - 4));
    wp[d] = (j < TT) ? 1.f : 0.f;
    wj[d] = (q == 4) ? ((j < TT) ? ex2(endp[j] * IL2) : 0.f) : wp[d];
  }
#define DOT8(X1, X2, WW, OUT)                                               \
  { float s_;                                                               \
    s_ = bf16tof((uint32_t)(X1).x & 0xFFFFu) * WW[0];                       \
    s_ = fmaf(bf16tof((uint32_t)(X1).x >> 16), WW[1], s_);                  \
    s_ = fmaf(bf16tof((uint32_t)(X1).y & 0xFFFFu), WW[2], s_);              \
    s_ = fmaf(bf16tof((uint32_t)(X1).y >> 16), WW[3], s_);                  \
    s_ = fmaf(bf16tof((uint32_t)(X2).x & 0xFFFFu), WW[4], s_);              \
    s_ = fmaf(bf16tof((uint32_t)(X2).x >> 16), WW[5], s_);                  \
    s_ = fmaf(bf16tof((uint32_t)(X2).y & 0xFFFFu), WW[6], s_);              \
    s_ = fmaf(bf16tof((uint32_t)(X2).y >> 16), WW[7], s_);                  \
    s_ += SWZ(s_, 0x401F);                                                  \
    s_ += bpermf(4 * (lane ^ 32), s_);                                      \
    OUT = s_; }

  float term, dref = 0.f;
  DOT8(B1, B2, wj, term)
  if (q > 1) {
    float phir;
    DOT8(Br1, Br2, wp, phir)
    dref = (float)Cref + lg2(phir);
  }
#undef DOT8
  float den2 = (float)C2 + lg2(term) - dref;     // log2 units
  float numc = num - numref;
  if (q == 4) numc += endp[labels[(b0 + m) * SS + LM1]];

  if (lane < 16) {
    wsseg[(b0 + m) * NSEG + (q - 1)] = numc - LN2F * den2;
    if (q == 1) wsl[b0 + m] = (float)Lm;
  }
}

__global__ void crf_reduce(const float* __restrict__ wsseg,
                           const float* __restrict__ wsl,
                           float* __restrict__ out)
{
  __shared__ float sr[256], sl[256];
  int t = threadIdx.x;
  float a = 0.0f, c = 0.0f;
  for (int i = t; i < BB * NSEG; i += 256) a += wsseg[i];
  for (int i = t; i < BB; i += 256) c += wsl[i];
  sr[t] = a; sl[t] = c;
  __syncthreads();
  for (int k = 128; k > 0; k >>= 1) {
    if (t < k) { sr[t] += sr[t + k]; sl[t] += sl[t + k]; }
    __syncthreads();
  }
  if (t == 0) out[0] = sr[0] / sl[0];
}

extern "C" void kernel_launch(void* const* d_in, const int* in_sizes, int n_in,
                              void* d_out, int out_size, void* d_ws, size_t ws_size,
                              hipStream_t stream)
{
  const float* em = (const float*)d_in[0];
  const float* st = (const float*)d_in[1];
  const float* en = (const float*)d_in[2];
  const float* tr = (const float*)d_in[3];
  const int*   lb = (const int*)d_in[4];
  const void*  mk = (const void*)d_in[5];
  float* wsseg = (float*)d_ws;             // BB*NSEG floats
  float* wsl   = wsseg + BB * NSEG;        // BB floats
  crf_seg<<<NRG * NSEG, 64, 0, stream>>>(em, st, en, tr, lb, mk, wsseg, wsl);
  crf_reduce<<<1, 256, 0, stream>>>(wsseg, wsl, (float*)d_out);
}